// Round 6
// baseline (711.597 us; speedup 1.0000x reference)
//
#include <hip/hip_runtime.h>

typedef float f32x4 __attribute__((ext_vector_type(4)));
typedef __bf16 bf16x8 __attribute__((ext_vector_type(8)));
typedef unsigned short u16;

#define NUM_CLASSES 1000
#define CPAD 1024
#define FEAT 256

// float -> bf16 round-to-nearest-even (bit pattern)
__device__ __forceinline__ u16 f2bf(float f) {
  unsigned u = __float_as_uint(f);
  u += 0x7fffu + ((u >> 16) & 1u);
  return (u16)(u >> 16);
}

__device__ __forceinline__ float wave_sum(float v) {
#pragma unroll
  for (int m = 1; m < 64; m <<= 1) v += __shfl_xor(v, m, 64);
  return v;
}

// async global->LDS 16B: linear LDS dest = base + lane*16 (wave-uniform base).
__device__ __forceinline__ void gload16(const void* g, void* l) {
  __builtin_amdgcn_global_load_lds(
      (const __attribute__((address_space(1))) void*)g,
      (__attribute__((address_space(3))) void*)l, 16, 0, 0);
}

// Kernel 1: normalize rows -> bf16 fn + f32 ||fn||^2, and histogram labels.
__global__ __launch_bounds__(256) void knorm(
    const float* __restrict__ feats, const int* __restrict__ labels,
    u16* __restrict__ fnbf, float* __restrict__ nf, int* __restrict__ counts) {
  int row = blockIdx.x * 4 + (threadIdx.x >> 6);
  int lane = threadIdx.x & 63;
  const float4 v = *(const float4*)(feats + (size_t)row * FEAT + lane * 4);
  float ss = v.x * v.x + v.y * v.y + v.z * v.z + v.w * v.w;
  ss = wave_sum(ss);
  float r = 1.0f / fmaxf(sqrtf(ss), 1e-12f);
  ushort4 o = make_ushort4(f2bf(v.x * r), f2bf(v.y * r), f2bf(v.z * r),
                           f2bf(v.w * r));
  *(ushort4*)(fnbf + (size_t)row * FEAT + lane * 4) = o;
  if (lane == 0) {
    nf[row] = ss * r * r;
    atomicAdd(&counts[labels[row]], 1);
  }
}

// Kernel 1b: single-block exclusive prefix over counts -> offsets, cursor.
__global__ __launch_bounds__(1024) void kprefix(
    const int* __restrict__ counts, int* __restrict__ offsets,
    int* __restrict__ cursor) {
  __shared__ int sc[1024];
  int tid = threadIdx.x;
  int v = (tid < NUM_CLASSES) ? counts[tid] : 0;
  sc[tid] = v;
  __syncthreads();
  for (int off = 1; off < 1024; off <<= 1) {
    int t = (tid >= off) ? sc[tid - off] : 0;
    __syncthreads();
    sc[tid] += t;
    __syncthreads();
  }
  int excl = sc[tid] - v;  // exclusive prefix
  offsets[tid] = excl;
  cursor[tid] = excl;
}

// Kernel 1c: scatter row indices into per-class contiguous lists.
__global__ __launch_bounds__(256) void kscatter(
    const int* __restrict__ labels, int* __restrict__ cursor,
    int* __restrict__ rowlist) {
  int i = blockIdx.x * 256 + threadIdx.x;
  int slot = atomicAdd(&cursor[labels[i]], 1);
  rowlist[slot] = i;
}

// Kernel 2: per-class gather-sum (from bf16 fn) + prototype EMA update.
// NOTE: `initialized` (jax bool) arrives as int32 per harness dtype rules.
__global__ __launch_bounds__(256) void kupdate(
    const float* __restrict__ protos, const int* __restrict__ inited,
    const int* __restrict__ epoch_p, const u16* __restrict__ fnbf,
    const int* __restrict__ rowlist, const int* __restrict__ offsets,
    const int* __restrict__ counts, u16* __restrict__ pnbf,
    float* __restrict__ npn) {
  int c = blockIdx.x;
  int tid = threadIdx.x;
  int lane = tid & 63, w = tid >> 6;
  if (c >= NUM_CLASSES) {  // zero pad rows so GEMM needs no load guards
    if (w == 0) *(ushort4*)(pnbf + (size_t)c * FEAT + lane * 4) =
        make_ushort4(0, 0, 0, 0);
    if (tid == 0) npn[c] = 0.0f;
    return;
  }
  int start = offsets[c];
  int icnt = counts[c];
  int end = start + icnt;
  f32x4 accv = {0.f, 0.f, 0.f, 0.f};
  for (int rIt = start + w; rIt < end; rIt += 4) {
    int row = rowlist[rIt];
    ushort4 u = *(const ushort4*)(fnbf + (size_t)row * FEAT + lane * 4);
    accv[0] += __uint_as_float((unsigned)u.x << 16);
    accv[1] += __uint_as_float((unsigned)u.y << 16);
    accv[2] += __uint_as_float((unsigned)u.z << 16);
    accv[3] += __uint_as_float((unsigned)u.w << 16);
  }
  __shared__ f32x4 smem[4][64];
  smem[w][lane] = accv;
  __syncthreads();
  if (w != 0) return;
  f32x4 s = smem[0][lane];
#pragma unroll
  for (int ww = 1; ww < 4; ww++) s += smem[ww][lane];

  float cnt = (float)icnt;
  const float4 p = *(const float4*)(protos + (size_t)c * FEAT + lane * 4);
  float ic = 1.0f / fmaxf(cnt, 1.0f);
  float mx = s[0] * ic, my = s[1] * ic, mz = s[2] * ic, mw = s[3] * ic;
  float ss = wave_sum(mx * mx + my * my + mz * mz + mw * mw);
  float r = 1.0f / fmaxf(sqrtf(ss), 1e-12f);
  mx *= r; my *= r; mz *= r; mw *= r;  // class_mean (normalized)
  int epoch = *epoch_p;
  float mom = (epoch < 5) ? 0.0f : 0.99f;
  float cx, cy, cz, cw;
  if (mom == 0.0f) {
    cx = mx; cy = my; cz = mz; cw = mw;
  } else {
    float ex = mom * p.x + (1.0f - mom) * mx;
    float ey = mom * p.y + (1.0f - mom) * my;
    float ez = mom * p.z + (1.0f - mom) * mz;
    float ew = mom * p.w + (1.0f - mom) * mw;
    float ss2 = wave_sum(ex * ex + ey * ey + ez * ez + ew * ew);
    float r2 = 1.0f / fmaxf(sqrtf(ss2), 1e-12f);
    ex *= r2; ey *= r2; ez *= r2; ew *= r2;
    bool ini = inited[c] != 0;
    cx = ini ? ex : mx; cy = ini ? ey : my;
    cz = ini ? ez : mz; cw = ini ? ew : mw;
  }
  bool present = icnt > 0;
  float nx = present ? cx : p.x, ny = present ? cy : p.y;
  float nz = present ? cz : p.z, nw = present ? cw : p.w;
  float ss3 = wave_sum(nx * nx + ny * ny + nz * nz + nw * nw);
  float r3 = 1.0f / fmaxf(sqrtf(ss3), 1e-12f);
  nx *= r3; ny *= r3; nz *= r3; nw *= r3;
  if (lane == 0) npn[c] = ss3 * r3 * r3;
  *(ushort4*)(pnbf + (size_t)c * FEAT + lane * 4) =
      make_ushort4(f2bf(nx), f2bf(ny), f2bf(nz), f2bf(nw));
}

// Kernel 3: logits via bf16 MFMA. Main loop identical to rounds 4/5.
// Epilogue: per-wave LDS transpose, slab stride 21 words (gcd(21,32)=1 ->
// <=2-way banks, free per m136), then PLAIN f32x4 stores (write-back L2
// merges 256B segments into full lines; round-5's `nt` caused 6x RMW
// amplification: FETCH=|out|, WRITE=6x|out| -- never stream partial lines).
#define TSTRIDE 21
__global__ __launch_bounds__(256) void kgemm(
    const u16* __restrict__ A, const u16* __restrict__ B,
    const float* __restrict__ nf, const float* __restrict__ npn,
    float* __restrict__ out) {
  __shared__ __align__(16) u16 S[2 * 128 * 64];  // As | Bs, reused by epilogue
  int bm = blockIdx.x, bn = blockIdx.y;
  int tid = threadIdx.x;
  int lane = tid & 63, w = tid >> 6;
  int wm = w >> 1, wn = w & 1;
  f32x4 acc[4][4];
#pragma unroll
  for (int m = 0; m < 4; m++)
#pragma unroll
    for (int n = 0; n < 4; n++) acc[m][n] = f32x4{0.f, 0.f, 0.f, 0.f};

  // staging geometry: issue j covers LDS bytes [j*4096 + w*1024 + lane*16).
  int srow = (w << 3) + (lane >> 3);            // + j*32 below
  int sgcol = ((lane & 7) ^ (srow & 7)) << 4;   // pre-swizzled source col
  const char* Ab = (const char*)A;
  const char* Bb = (const char*)B;
  char* Asb = (char*)S;
  char* Bsb = (char*)S + 128 * 64 * 2;

  // fragment read geometry
  int fr = lane & 15;
  int koff = (lane >> 4) << 4;        // byte offset of 8-elem k-slice
  int xr = (lane & 7) << 4;           // xor value ((row&7)<<4), row&7 == lane&7
  int arow = (wm * 64 + fr) * 128;
  int brow = (wn * 64 + fr) * 128;

#pragma unroll 1
  for (int t = 0; t < 4; t++) {
    int k0 = t * 64;
#pragma unroll
    for (int j = 0; j < 4; j++) {
      int row = (j << 5) + srow;
      int ldo = (j << 12) + (w << 10);
      size_t gA = ((size_t)(bm * 128 + row) * FEAT + k0) * 2 + sgcol;
      size_t gB = ((size_t)(bn * 128 + row) * FEAT + k0) * 2 + sgcol;
      gload16(Ab + gA, Asb + ldo);
      gload16(Bb + gB, Bsb + ldo);
    }
    __syncthreads();
#pragma unroll
    for (int ks = 0; ks < 2; ks++) {
      int off = ((ks << 6) + koff) ^ xr;
      bf16x8 av[4], bv[4];
#pragma unroll
      for (int m = 0; m < 4; m++)
        av[m] = *(const bf16x8*)(Asb + arow + m * (16 * 128) + off);
#pragma unroll
      for (int n = 0; n < 4; n++)
        bv[n] = *(const bf16x8*)(Bsb + brow + n * (16 * 128) + off);
#pragma unroll
      for (int m = 0; m < 4; m++)
#pragma unroll
        for (int n = 0; n < 4; n++)
          acc[m][n] = __builtin_amdgcn_mfma_f32_16x16x32_bf16(
              av[m], bv[n], acc[m][n], 0, 0, 0);
    }
    __syncthreads();
  }
  // last __syncthreads: all waves done reading S; each wave now uses only its
  // private slab (64*TSTRIDE floats), so no further barriers needed.

  // Epilogue. MFMA C/D layout: col=lane&15 (+16n), row=(lane>>4)*4+q (+16m).
  float* T = (float*)(S) + w * (64 * TSTRIDE);  // per-wave [64 cols][TSTRIDE]
  int cT = lane & 15;
  int r0 = (lane >> 4) << 2;
  int rr = lane >> 4;             // readback row within 4-row group
  int cc = (lane & 15) << 2;      // readback col group (4 consecutive cols)
#pragma unroll 1
  for (int m = 0; m < 4; m++) {
    // stage transposed: T[c*TSTRIDE + r] = C_rel[wm*64+m*16+r][wn*64+c]
#pragma unroll
    for (int n = 0; n < 4; n++)
      *(f32x4*)(T + (cT + n * 16) * TSTRIDE + r0) = acc[m][n];
#pragma unroll
    for (int it = 0; it < 4; it++) {
      int row = (it << 2) + rr;  // 0..15
      f32x4 v = {T[(cc + 0) * TSTRIDE + row], T[(cc + 1) * TSTRIDE + row],
                 T[(cc + 2) * TSTRIDE + row], T[(cc + 3) * TSTRIDE + row]};
      int gcol = bn * 128 + wn * 64 + cc;
      if (gcol >= NUM_CLASSES) continue;  // whole 4-col group in pad region
      int grow = bm * 128 + wm * 64 + m * 16 + row;
      const f32x4 np4 = *(const f32x4*)(npn + gcol);
      float nfv = nf[grow];
      f32x4 o;
#pragma unroll
      for (int i = 0; i < 4; i++) {
        float sq = nfv + np4[i] - 2.0f * v[i];
        o[i] = -sqrtf(fmaxf(sq, 0.0f));
      }
      *(f32x4*)(out + (size_t)grow * NUM_CLASSES + gcol) = o;
    }
  }
}

extern "C" void kernel_launch(void* const* d_in, const int* in_sizes, int n_in,
                              void* d_out, int out_size, void* d_ws,
                              size_t ws_size, hipStream_t stream) {
  const float* feats = (const float*)d_in[0];
  const float* protos = (const float*)d_in[1];
  const int* labels = (const int*)d_in[2];
  const int* inited = (const int*)d_in[3];  // jax bool -> int32 per harness
  const int* epoch_p = (const int*)d_in[4];
  float* out = (float*)d_out;
  int N = in_sizes[0] / FEAT;  // 131072

  char* ws = (char*)d_ws;
  // layout: fnbf[N*256 bf16] | nf[N f32] | rowlist[N i32] | counts[1024 i32]
  //         | offsets[1024 i32] | cursor[1024 i32] | pnbf[1024*256 bf16]
  //         | npn[1024 f32]
  size_t off = 0;
  u16* fnbf = (u16*)(ws + off);    off += (size_t)N * FEAT * 2;
  float* nf = (float*)(ws + off);  off += (size_t)N * 4;
  int* rowlist = (int*)(ws + off); off += (size_t)N * 4;
  int* counts = (int*)(ws + off);  off += (size_t)CPAD * 4;
  int* offsets = (int*)(ws + off); off += (size_t)CPAD * 4;
  int* cursor = (int*)(ws + off);  off += (size_t)CPAD * 4;
  u16* pnbf = (u16*)(ws + off);    off += (size_t)CPAD * FEAT * 2;
  float* npn = (float*)(ws + off); off += (size_t)CPAD * 4;
  (void)ws_size; (void)n_in; (void)out_size;

  hipMemsetAsync(counts, 0, (size_t)CPAD * 4, stream);  // 4 KB only

  knorm<<<N / 4, 256, 0, stream>>>(feats, labels, fnbf, nf, counts);
  kprefix<<<1, 1024, 0, stream>>>(counts, offsets, cursor);
  kscatter<<<N / 256, 256, 0, stream>>>(labels, cursor, rowlist);
  kupdate<<<CPAD, 256, 0, stream>>>(protos, inited, epoch_p, fnbf, rowlist,
                                    offsets, counts, pnbf, npn);
  dim3 g(N / 128, CPAD / 128);
  kgemm<<<g, 256, 0, stream>>>(fnbf, pnbf, nf, npn, out);
}

// Round 7
// 326.586 us; speedup vs baseline: 2.1789x; 2.1789x over previous
//
#include <hip/hip_runtime.h>

typedef float f32x4 __attribute__((ext_vector_type(4)));
typedef __bf16 bf16x8 __attribute__((ext_vector_type(8)));
typedef unsigned short u16;

#define NUM_CLASSES 1000
#define CPAD 1024
#define FEAT 256

// float -> bf16 round-to-nearest-even (bit pattern)
__device__ __forceinline__ u16 f2bf(float f) {
  unsigned u = __float_as_uint(f);
  u += 0x7fffu + ((u >> 16) & 1u);
  return (u16)(u >> 16);
}

__device__ __forceinline__ float wave_sum(float v) {
#pragma unroll
  for (int m = 1; m < 64; m <<= 1) v += __shfl_xor(v, m, 64);
  return v;
}

// async global->LDS 16B: LDS dest = wave-uniform base + lane*16.
__device__ __forceinline__ void gload16(const void* g, void* l) {
  __builtin_amdgcn_global_load_lds(
      (const __attribute__((address_space(1))) void*)g,
      (__attribute__((address_space(3))) void*)l, 16, 0, 0);
}

// Kernel 1: normalize rows -> bf16 fn + f32 ||fn||^2, and histogram labels.
__global__ __launch_bounds__(256) void knorm(
    const float* __restrict__ feats, const int* __restrict__ labels,
    u16* __restrict__ fnbf, float* __restrict__ nf, int* __restrict__ counts) {
  int row = blockIdx.x * 4 + (threadIdx.x >> 6);
  int lane = threadIdx.x & 63;
  const float4 v = *(const float4*)(feats + (size_t)row * FEAT + lane * 4);
  float ss = v.x * v.x + v.y * v.y + v.z * v.z + v.w * v.w;
  ss = wave_sum(ss);
  float r = 1.0f / fmaxf(sqrtf(ss), 1e-12f);
  ushort4 o = make_ushort4(f2bf(v.x * r), f2bf(v.y * r), f2bf(v.z * r),
                           f2bf(v.w * r));
  *(ushort4*)(fnbf + (size_t)row * FEAT + lane * 4) = o;
  if (lane == 0) {
    nf[row] = ss * r * r;
    atomicAdd(&counts[labels[row]], 1);
  }
}

// Kernel 1b: single-block exclusive prefix over counts -> offsets, cursor.
__global__ __launch_bounds__(1024) void kprefix(
    const int* __restrict__ counts, int* __restrict__ offsets,
    int* __restrict__ cursor) {
  __shared__ int sc[1024];
  int tid = threadIdx.x;
  int v = (tid < NUM_CLASSES) ? counts[tid] : 0;
  sc[tid] = v;
  __syncthreads();
  for (int off = 1; off < 1024; off <<= 1) {
    int t = (tid >= off) ? sc[tid - off] : 0;
    __syncthreads();
    sc[tid] += t;
    __syncthreads();
  }
  int excl = sc[tid] - v;  // exclusive prefix
  offsets[tid] = excl;
  cursor[tid] = excl;
}

// Kernel 1c: scatter row indices into per-class contiguous lists.
__global__ __launch_bounds__(256) void kscatter(
    const int* __restrict__ labels, int* __restrict__ cursor,
    int* __restrict__ rowlist) {
  int i = blockIdx.x * 256 + threadIdx.x;
  int slot = atomicAdd(&cursor[labels[i]], 1);
  rowlist[slot] = i;
}

// Kernel 2: per-class gather-sum (from bf16 fn) + prototype EMA update.
// NOTE: `initialized` (jax bool) arrives as int32 per harness dtype rules.
__global__ __launch_bounds__(256) void kupdate(
    const float* __restrict__ protos, const int* __restrict__ inited,
    const int* __restrict__ epoch_p, const u16* __restrict__ fnbf,
    const int* __restrict__ rowlist, const int* __restrict__ offsets,
    const int* __restrict__ counts, u16* __restrict__ pnbf,
    float* __restrict__ npn) {
  int c = blockIdx.x;
  int tid = threadIdx.x;
  int lane = tid & 63, w = tid >> 6;
  if (c >= NUM_CLASSES) {  // zero pad rows so GEMM needs no load guards
    if (w == 0) *(ushort4*)(pnbf + (size_t)c * FEAT + lane * 4) =
        make_ushort4(0, 0, 0, 0);
    if (tid == 0) npn[c] = 0.0f;
    return;
  }
  int start = offsets[c];
  int icnt = counts[c];
  int end = start + icnt;
  f32x4 accv = {0.f, 0.f, 0.f, 0.f};
  for (int rIt = start + w; rIt < end; rIt += 4) {
    int row = rowlist[rIt];
    ushort4 u = *(const ushort4*)(fnbf + (size_t)row * FEAT + lane * 4);
    accv[0] += __uint_as_float((unsigned)u.x << 16);
    accv[1] += __uint_as_float((unsigned)u.y << 16);
    accv[2] += __uint_as_float((unsigned)u.z << 16);
    accv[3] += __uint_as_float((unsigned)u.w << 16);
  }
  __shared__ f32x4 smem[4][64];
  smem[w][lane] = accv;
  __syncthreads();
  if (w != 0) return;
  f32x4 s = smem[0][lane];
#pragma unroll
  for (int ww = 1; ww < 4; ww++) s += smem[ww][lane];

  float cnt = (float)icnt;
  const float4 p = *(const float4*)(protos + (size_t)c * FEAT + lane * 4);
  float ic = 1.0f / fmaxf(cnt, 1.0f);
  float mx = s[0] * ic, my = s[1] * ic, mz = s[2] * ic, mw = s[3] * ic;
  float ss = wave_sum(mx * mx + my * my + mz * mz + mw * mw);
  float r = 1.0f / fmaxf(sqrtf(ss), 1e-12f);
  mx *= r; my *= r; mz *= r; mw *= r;  // class_mean (normalized)
  int epoch = *epoch_p;
  float mom = (epoch < 5) ? 0.0f : 0.99f;
  float cx, cy, cz, cw;
  if (mom == 0.0f) {
    cx = mx; cy = my; cz = mz; cw = mw;
  } else {
    float ex = mom * p.x + (1.0f - mom) * mx;
    float ey = mom * p.y + (1.0f - mom) * my;
    float ez = mom * p.z + (1.0f - mom) * mz;
    float ew = mom * p.w + (1.0f - mom) * mw;
    float ss2 = wave_sum(ex * ex + ey * ey + ez * ez + ew * ew);
    float r2 = 1.0f / fmaxf(sqrtf(ss2), 1e-12f);
    ex *= r2; ey *= r2; ez *= r2; ew *= r2;
    bool ini = inited[c] != 0;
    cx = ini ? ex : mx; cy = ini ? ey : my;
    cz = ini ? ez : mz; cw = ini ? ew : mw;
  }
  bool present = icnt > 0;
  float nx = present ? cx : p.x, ny = present ? cy : p.y;
  float nz = present ? cz : p.z, nw = present ? cw : p.w;
  float ss3 = wave_sum(nx * nx + ny * ny + nz * nz + nw * nw);
  float r3 = 1.0f / fmaxf(sqrtf(ss3), 1e-12f);
  nx *= r3; ny *= r3; nz *= r3; nw *= r3;
  if (lane == 0) npn[c] = ss3 * r3 * r3;
  *(ushort4*)(pnbf + (size_t)c * FEAT + lane * 4) =
      make_ushort4(f2bf(nx), f2bf(ny), f2bf(nz), f2bf(nw));
}

// Kernel 3: logits. BM=64 x BN=512 tile, BK=32, 512 thr / 8 waves.
// Wave w owns cols [bn*512 + w*64, +64) over all 64 rows.
// A[64][256] prestaged once (32KB). B: per-wave private 4KB slab, restaged
// each K-iter; K-loop has ZERO barriers (per-wave vmcnt(0) only; B[t+1]
// prefetch issued before the MFMAs -> overlaps DMA with compute).
// Stores: scalar 4B (round-4-proven: no TCC write amplification), rows
// complete within the block -> no cross-block partial lines.
__global__ __launch_bounds__(512, 4) void kgemm(
    const u16* __restrict__ A, const u16* __restrict__ B,
    const float* __restrict__ nf, const float* __restrict__ npn,
    float* __restrict__ out) {
  __shared__ __align__(16) u16 S[32768];  // 64KB: A 32KB | 8 x 4KB B slabs
  int bm = blockIdx.x, bn = blockIdx.y;
  int tid = threadIdx.x;
  int lane = tid & 63, w = tid >> 6;
  char* Asb = (char*)S;             // A[64][512B] linear
  char* Bw = (char*)S + 32768 + w * 4096;  // this wave's B[64][64B]

  const char* Ag = (const char*)A + (size_t)bm * 64 * 512;
  const char* Bg = (const char*)B + ((size_t)bn * 512 + w * 64) * 512;

  // ---- prologue: stage all of A (4 issues/wave) + B[0] (4 issues/wave) ----
#pragma unroll
  for (int r = 0; r < 4; r++) {
    int row = r * 16 + w * 2 + (lane >> 5);
    gload16(Ag + (size_t)row * 512 + (lane & 31) * 16,
            Asb + r * 8192 + w * 1024);
  }
#pragma unroll
  for (int j = 0; j < 4; j++)
    gload16(Bg + (size_t)(j * 16 + (lane >> 2)) * 512 + (lane & 3) * 16,
            Bw + j * 1024);
  asm volatile("s_waitcnt vmcnt(0)" ::: "memory");
  __syncthreads();

  f32x4 acc[4][4];
#pragma unroll
  for (int m = 0; m < 4; m++)
#pragma unroll
    for (int n = 0; n < 4; n++) acc[m][n] = f32x4{0.f, 0.f, 0.f, 0.f};

  int fr = lane & 15;
  int ko = (lane >> 4) << 4;  // 16B k-slice within the 64B k-window

  // ---- K loop: 8 iters of BK=32, no barriers ----
#pragma unroll 1
  for (int t = 0; t < 8; t++) {
    bf16x8 av[4], bv[4];
#pragma unroll
    for (int m = 0; m < 4; m++)
      av[m] = *(const bf16x8*)(Asb + (m * 16 + fr) * 512 + t * 64 + ko);
#pragma unroll
    for (int n = 0; n < 4; n++)
      bv[n] = *(const bf16x8*)(Bw + (n * 16 + fr) * 64 + ko);
    // force LDS reads complete before re-staging Bw (lgkmcnt drained here)
    asm volatile("" ::"v"(av[0]), "v"(av[1]), "v"(av[2]), "v"(av[3]),
                 "v"(bv[0]), "v"(bv[1]), "v"(bv[2]), "v"(bv[3]));
    if (t < 7) {  // prefetch B[t+1] into the (now reg-copied) slab
#pragma unroll
      for (int j = 0; j < 4; j++)
        gload16(Bg + (size_t)(j * 16 + (lane >> 2)) * 512 + (t + 1) * 64 +
                    (lane & 3) * 16,
                Bw + j * 1024);
    }
#pragma unroll
    for (int m = 0; m < 4; m++)
#pragma unroll
      for (int n = 0; n < 4; n++)
        acc[m][n] = __builtin_amdgcn_mfma_f32_16x16x32_bf16(av[m], bv[n],
                                                            acc[m][n], 0, 0, 0);
    if (t < 7) asm volatile("s_waitcnt vmcnt(0)" ::: "memory");
  }

  // ---- epilogue: scalar stores (C/D: col=lane&15, row=(lane>>4)*4+q) ----
  int col0 = bn * 512 + w * 64 + fr;
  int rbase = bm * 64 + (lane >> 4) * 4;
#pragma unroll
  for (int m = 0; m < 4; m++) {
    int row0 = rbase + m * 16;
    const float4 nfv = *(const float4*)(nf + row0);
#pragma unroll
    for (int n = 0; n < 4; n++) {
      int col = col0 + n * 16;
      if (col >= NUM_CLASSES) continue;  // per-lane guard (tail cols)
      float npv = npn[col];
      float sq0 = nfv.x + npv - 2.0f * acc[m][n][0];
      float sq1 = nfv.y + npv - 2.0f * acc[m][n][1];
      float sq2 = nfv.z + npv - 2.0f * acc[m][n][2];
      float sq3 = nfv.w + npv - 2.0f * acc[m][n][3];
      float* o = out + (size_t)row0 * NUM_CLASSES + col;
      o[0] = -sqrtf(fmaxf(sq0, 0.0f));
      o[NUM_CLASSES] = -sqrtf(fmaxf(sq1, 0.0f));
      o[2 * NUM_CLASSES] = -sqrtf(fmaxf(sq2, 0.0f));
      o[3 * NUM_CLASSES] = -sqrtf(fmaxf(sq3, 0.0f));
    }
  }
}

extern "C" void kernel_launch(void* const* d_in, const int* in_sizes, int n_in,
                              void* d_out, int out_size, void* d_ws,
                              size_t ws_size, hipStream_t stream) {
  const float* feats = (const float*)d_in[0];
  const float* protos = (const float*)d_in[1];
  const int* labels = (const int*)d_in[2];
  const int* inited = (const int*)d_in[3];  // jax bool -> int32 per harness
  const int* epoch_p = (const int*)d_in[4];
  float* out = (float*)d_out;
  int N = in_sizes[0] / FEAT;  // 131072

  char* ws = (char*)d_ws;
  // layout: fnbf[N*256 bf16] | nf[N f32] | rowlist[N i32] | counts[1024 i32]
  //         | offsets[1024 i32] | cursor[1024 i32] | pnbf[1024*256 bf16]
  //         | npn[1024 f32]
  size_t off = 0;
  u16* fnbf = (u16*)(ws + off);    off += (size_t)N * FEAT * 2;
  float* nf = (float*)(ws + off);  off += (size_t)N * 4;
  int* rowlist = (int*)(ws + off); off += (size_t)N * 4;
  int* counts = (int*)(ws + off);  off += (size_t)CPAD * 4;
  int* offsets = (int*)(ws + off); off += (size_t)CPAD * 4;
  int* cursor = (int*)(ws + off);  off += (size_t)CPAD * 4;
  u16* pnbf = (u16*)(ws + off);    off += (size_t)CPAD * FEAT * 2;
  float* npn = (float*)(ws + off); off += (size_t)CPAD * 4;
  (void)ws_size; (void)n_in; (void)out_size;

  hipMemsetAsync(counts, 0, (size_t)CPAD * 4, stream);  // 4 KB only

  knorm<<<N / 4, 256, 0, stream>>>(feats, labels, fnbf, nf, counts);
  kprefix<<<1, 1024, 0, stream>>>(counts, offsets, cursor);
  kscatter<<<N / 256, 256, 0, stream>>>(labels, cursor, rowlist);
  kupdate<<<CPAD, 256, 0, stream>>>(protos, inited, epoch_p, fnbf, rowlist,
                                    offsets, counts, pnbf, npn);
  dim3 g(N / 64, 2);
  kgemm<<<g, 512, 0, stream>>>(fnbf, pnbf, nf, npn, out);
}

// Round 8
// 326.211 us; speedup vs baseline: 2.1814x; 1.0012x over previous
//
#include <hip/hip_runtime.h>

typedef float f32x4 __attribute__((ext_vector_type(4)));
typedef __bf16 bf16x8 __attribute__((ext_vector_type(8)));
typedef unsigned short u16;

#define NUM_CLASSES 1000
#define CPAD 1024
#define FEAT 256

// float -> bf16 round-to-nearest-even (bit pattern)
__device__ __forceinline__ u16 f2bf(float f) {
  unsigned u = __float_as_uint(f);
  u += 0x7fffu + ((u >> 16) & 1u);
  return (u16)(u >> 16);
}

__device__ __forceinline__ float wave_sum(float v) {
#pragma unroll
  for (int m = 1; m < 64; m <<= 1) v += __shfl_xor(v, m, 64);
  return v;
}

// async global->LDS 16B: LDS dest = wave-uniform base + lane*16.
__device__ __forceinline__ void gload16(const void* g, void* l) {
  __builtin_amdgcn_global_load_lds(
      (const __attribute__((address_space(1))) void*)g,
      (__attribute__((address_space(3))) void*)l, 16, 0, 0);
}

// Kernel 1: normalize rows -> bf16 fn + f32 ||fn||^2, and histogram labels.
__global__ __launch_bounds__(256) void knorm(
    const float* __restrict__ feats, const int* __restrict__ labels,
    u16* __restrict__ fnbf, float* __restrict__ nf, int* __restrict__ counts) {
  int row = blockIdx.x * 4 + (threadIdx.x >> 6);
  int lane = threadIdx.x & 63;
  const float4 v = *(const float4*)(feats + (size_t)row * FEAT + lane * 4);
  float ss = v.x * v.x + v.y * v.y + v.z * v.z + v.w * v.w;
  ss = wave_sum(ss);
  float r = 1.0f / fmaxf(sqrtf(ss), 1e-12f);
  ushort4 o = make_ushort4(f2bf(v.x * r), f2bf(v.y * r), f2bf(v.z * r),
                           f2bf(v.w * r));
  *(ushort4*)(fnbf + (size_t)row * FEAT + lane * 4) = o;
  if (lane == 0) {
    nf[row] = ss * r * r;
    atomicAdd(&counts[labels[row]], 1);
  }
}

// Kernel 1b: single-block exclusive prefix over counts -> offsets, cursor.
__global__ __launch_bounds__(1024) void kprefix(
    const int* __restrict__ counts, int* __restrict__ offsets,
    int* __restrict__ cursor) {
  __shared__ int sc[1024];
  int tid = threadIdx.x;
  int v = (tid < NUM_CLASSES) ? counts[tid] : 0;
  sc[tid] = v;
  __syncthreads();
  for (int off = 1; off < 1024; off <<= 1) {
    int t = (tid >= off) ? sc[tid - off] : 0;
    __syncthreads();
    sc[tid] += t;
    __syncthreads();
  }
  int excl = sc[tid] - v;  // exclusive prefix
  offsets[tid] = excl;
  cursor[tid] = excl;
}

// Kernel 1c: scatter row indices into per-class contiguous lists.
__global__ __launch_bounds__(256) void kscatter(
    const int* __restrict__ labels, int* __restrict__ cursor,
    int* __restrict__ rowlist) {
  int i = blockIdx.x * 256 + threadIdx.x;
  int slot = atomicAdd(&cursor[labels[i]], 1);
  rowlist[slot] = i;
}

// Kernel 2: per-class gather-sum (from bf16 fn) + prototype EMA update.
// NOTE: `initialized` (jax bool) arrives as int32 per harness dtype rules.
__global__ __launch_bounds__(256) void kupdate(
    const float* __restrict__ protos, const int* __restrict__ inited,
    const int* __restrict__ epoch_p, const u16* __restrict__ fnbf,
    const int* __restrict__ rowlist, const int* __restrict__ offsets,
    const int* __restrict__ counts, u16* __restrict__ pnbf,
    float* __restrict__ npn) {
  int c = blockIdx.x;
  int tid = threadIdx.x;
  int lane = tid & 63, w = tid >> 6;
  if (c >= NUM_CLASSES) {  // zero pad rows so GEMM needs no load guards
    if (w == 0) *(ushort4*)(pnbf + (size_t)c * FEAT + lane * 4) =
        make_ushort4(0, 0, 0, 0);
    if (tid == 0) npn[c] = 0.0f;
    return;
  }
  int start = offsets[c];
  int icnt = counts[c];
  int end = start + icnt;
  f32x4 accv = {0.f, 0.f, 0.f, 0.f};
  for (int rIt = start + w; rIt < end; rIt += 4) {
    int row = rowlist[rIt];
    ushort4 u = *(const ushort4*)(fnbf + (size_t)row * FEAT + lane * 4);
    accv[0] += __uint_as_float((unsigned)u.x << 16);
    accv[1] += __uint_as_float((unsigned)u.y << 16);
    accv[2] += __uint_as_float((unsigned)u.z << 16);
    accv[3] += __uint_as_float((unsigned)u.w << 16);
  }
  __shared__ f32x4 smem[4][64];
  smem[w][lane] = accv;
  __syncthreads();
  if (w != 0) return;
  f32x4 s = smem[0][lane];
#pragma unroll
  for (int ww = 1; ww < 4; ww++) s += smem[ww][lane];

  float cnt = (float)icnt;
  const float4 p = *(const float4*)(protos + (size_t)c * FEAT + lane * 4);
  float ic = 1.0f / fmaxf(cnt, 1.0f);
  float mx = s[0] * ic, my = s[1] * ic, mz = s[2] * ic, mw = s[3] * ic;
  float ss = wave_sum(mx * mx + my * my + mz * mz + mw * mw);
  float r = 1.0f / fmaxf(sqrtf(ss), 1e-12f);
  mx *= r; my *= r; mz *= r; mw *= r;  // class_mean (normalized)
  int epoch = *epoch_p;
  float mom = (epoch < 5) ? 0.0f : 0.99f;
  float cx, cy, cz, cw;
  if (mom == 0.0f) {
    cx = mx; cy = my; cz = mz; cw = mw;
  } else {
    float ex = mom * p.x + (1.0f - mom) * mx;
    float ey = mom * p.y + (1.0f - mom) * my;
    float ez = mom * p.z + (1.0f - mom) * mz;
    float ew = mom * p.w + (1.0f - mom) * mw;
    float ss2 = wave_sum(ex * ex + ey * ey + ez * ez + ew * ew);
    float r2 = 1.0f / fmaxf(sqrtf(ss2), 1e-12f);
    ex *= r2; ey *= r2; ez *= r2; ew *= r2;
    bool ini = inited[c] != 0;
    cx = ini ? ex : mx; cy = ini ? ey : my;
    cz = ini ? ez : mz; cw = ini ? ew : mw;
  }
  bool present = icnt > 0;
  float nx = present ? cx : p.x, ny = present ? cy : p.y;
  float nz = present ? cz : p.z, nw = present ? cw : p.w;
  float ss3 = wave_sum(nx * nx + ny * ny + nz * nz + nw * nw);
  float r3 = 1.0f / fmaxf(sqrtf(ss3), 1e-12f);
  nx *= r3; ny *= r3; nz *= r3; nw *= r3;
  if (lane == 0) npn[c] = ss3 * r3 * r3;
  *(ushort4*)(pnbf + (size_t)c * FEAT + lane * 4) =
      make_ushort4(f2bf(nx), f2bf(ny), f2bf(nz), f2bf(nw));
}

// Kernel 3: logits. BM=64 x BN=512, BK=32, 512 thr / 8 waves (round-7
// structure) + NEW: XOR bank-swizzles on A and B LDS tiles (rule #21:
// linear gload_lds dest, pre-swizzled GLOBAL source, swizzled READ).
//   A [64 rows][32 chunks of 16B]: chunk' = chunk ^ (row&7)
//       (round 7 was 16-way conflicted: row stride 512B == 0 mod banks)
//   B slab [64 cols][4 chunks of 16B]: chunk' = chunk ^ (col&3)
//       (round 7 was 8-way conflicted: col stride 64B -> banks {0,16})
__global__ __launch_bounds__(512, 4) void kgemm(
    const u16* __restrict__ A, const u16* __restrict__ B,
    const float* __restrict__ nf, const float* __restrict__ npn,
    float* __restrict__ out) {
  __shared__ __align__(16) u16 S[32768];  // 64KB: A 32KB | 8 x 4KB B slabs
  int bm = blockIdx.x, bn = blockIdx.y;
  int tid = threadIdx.x;
  int lane = tid & 63, w = tid >> 6;
  char* Asb = (char*)S;                    // A[64][512B], chunk-swizzled
  char* Bw = (char*)S + 32768 + w * 4096;  // this wave's B[64][64B]

  const char* Ag = (const char*)A + (size_t)bm * 64 * 512;
  const char* Bg = (const char*)B + ((size_t)bn * 512 + w * 64) * 512;

  // ---- prologue: stage all of A (4 issues/wave) + B[0] (4 issues/wave) ----
#pragma unroll
  for (int r = 0; r < 4; r++) {
    int row = r * 16 + w * 2 + (lane >> 5);
    int csw = ((lane & 31) ^ (row & 7)) << 4;  // source chunk pre-swizzle
    gload16(Ag + (size_t)row * 512 + csw, Asb + r * 8192 + w * 1024);
  }
#pragma unroll
  for (int j = 0; j < 4; j++) {
    int col = j * 16 + (lane >> 2);
    int ksw = ((lane & 3) ^ (col & 3)) << 4;  // source chunk pre-swizzle
    gload16(Bg + (size_t)col * 512 + ksw, Bw + j * 1024);
  }
  asm volatile("s_waitcnt vmcnt(0)" ::: "memory");
  __syncthreads();

  f32x4 acc[4][4];
#pragma unroll
  for (int m = 0; m < 4; m++)
#pragma unroll
    for (int n = 0; n < 4; n++) acc[m][n] = f32x4{0.f, 0.f, 0.f, 0.f};

  int fr = lane & 15;
  int ks = lane >> 4;  // k-slice index 0..3 within 64B window

  // ---- K loop: 8 iters of BK=32, no barriers ----
#pragma unroll 1
  for (int t = 0; t < 8; t++) {
    bf16x8 av[4], bv[4];
#pragma unroll
    for (int m = 0; m < 4; m++)
      av[m] = *(const bf16x8*)(Asb + (m * 16 + fr) * 512 +
                               (((t * 4 + ks) ^ (fr & 7)) << 4));
#pragma unroll
    for (int n = 0; n < 4; n++)
      bv[n] = *(const bf16x8*)(Bw + (n * 16 + fr) * 64 +
                               ((ks ^ (fr & 3)) << 4));
    // force LDS reads complete before re-staging Bw (lgkmcnt drained here)
    asm volatile("" ::"v"(av[0]), "v"(av[1]), "v"(av[2]), "v"(av[3]),
                 "v"(bv[0]), "v"(bv[1]), "v"(bv[2]), "v"(bv[3]));
    if (t < 7) {  // prefetch B[t+1] into the (now reg-copied) slab
#pragma unroll
      for (int j = 0; j < 4; j++) {
        int col = j * 16 + (lane >> 2);
        int ksw = ((lane & 3) ^ (col & 3)) << 4;
        gload16(Bg + (size_t)col * 512 + (t + 1) * 64 + ksw, Bw + j * 1024);
      }
    }
#pragma unroll
    for (int m = 0; m < 4; m++)
#pragma unroll
      for (int n = 0; n < 4; n++)
        acc[m][n] = __builtin_amdgcn_mfma_f32_16x16x32_bf16(av[m], bv[n],
                                                            acc[m][n], 0, 0, 0);
    if (t < 7) asm volatile("s_waitcnt vmcnt(0)" ::: "memory");
  }

  // ---- epilogue: scalar stores (C/D: col=lane&15, row=(lane>>4)*4+q) ----
  int col0 = bn * 512 + w * 64 + fr;
  int rbase = bm * 64 + (lane >> 4) * 4;
#pragma unroll
  for (int m = 0; m < 4; m++) {
    int row0 = rbase + m * 16;
    const float4 nfv = *(const float4*)(nf + row0);
#pragma unroll
    for (int n = 0; n < 4; n++) {
      int col = col0 + n * 16;
      if (col >= NUM_CLASSES) continue;  // per-lane guard (tail cols)
      float npv = npn[col];
      float sq0 = nfv.x + npv - 2.0f * acc[m][n][0];
      float sq1 = nfv.y + npv - 2.0f * acc[m][n][1];
      float sq2 = nfv.z + npv - 2.0f * acc[m][n][2];
      float sq3 = nfv.w + npv - 2.0f * acc[m][n][3];
      float* o = out + (size_t)row0 * NUM_CLASSES + col;
      o[0] = -sqrtf(fmaxf(sq0, 0.0f));
      o[NUM_CLASSES] = -sqrtf(fmaxf(sq1, 0.0f));
      o[2 * NUM_CLASSES] = -sqrtf(fmaxf(sq2, 0.0f));
      o[3 * NUM_CLASSES] = -sqrtf(fmaxf(sq3, 0.0f));
    }
  }
}

extern "C" void kernel_launch(void* const* d_in, const int* in_sizes, int n_in,
                              void* d_out, int out_size, void* d_ws,
                              size_t ws_size, hipStream_t stream) {
  const float* feats = (const float*)d_in[0];
  const float* protos = (const float*)d_in[1];
  const int* labels = (const int*)d_in[2];
  const int* inited = (const int*)d_in[3];  // jax bool -> int32 per harness
  const int* epoch_p = (const int*)d_in[4];
  float* out = (float*)d_out;
  int N = in_sizes[0] / FEAT;  // 131072

  char* ws = (char*)d_ws;
  // layout: fnbf[N*256 bf16] | nf[N f32] | rowlist[N i32] | counts[1024 i32]
  //         | offsets[1024 i32] | cursor[1024 i32] | pnbf[1024*256 bf16]
  //         | npn[1024 f32]
  size_t off = 0;
  u16* fnbf = (u16*)(ws + off);    off += (size_t)N * FEAT * 2;
  float* nf = (float*)(ws + off);  off += (size_t)N * 4;
  int* rowlist = (int*)(ws + off); off += (size_t)N * 4;
  int* counts = (int*)(ws + off);  off += (size_t)CPAD * 4;
  int* offsets = (int*)(ws + off); off += (size_t)CPAD * 4;
  int* cursor = (int*)(ws + off);  off += (size_t)CPAD * 4;
  u16* pnbf = (u16*)(ws + off);    off += (size_t)CPAD * FEAT * 2;
  float* npn = (float*)(ws + off); off += (size_t)CPAD * 4;
  (void)ws_size; (void)n_in; (void)out_size;

  hipMemsetAsync(counts, 0, (size_t)CPAD * 4, stream);  // 4 KB only

  knorm<<<N / 4, 256, 0, stream>>>(feats, labels, fnbf, nf, counts);
  kprefix<<<1, 1024, 0, stream>>>(counts, offsets, cursor);
  kscatter<<<N / 256, 256, 0, stream>>>(labels, cursor, rowlist);
  kupdate<<<CPAD, 256, 0, stream>>>(protos, inited, epoch_p, fnbf, rowlist,
                                    offsets, counts, pnbf, npn);
  dim3 g(N / 64, 2);
  kgemm<<<g, 512, 0, stream>>>(fnbf, pnbf, nf, npn, out);
}